// Round 8
// baseline (702.009 us; speedup 1.0000x reference)
//
#include <hip/hip_runtime.h>
#include <hip/hip_bf16.h>
#include <math.h>

// Problem constants (fixed by reference)
#define D_MODEL   768
#define D_STATE   16
#define D_CONV    4
#define D_INNER   1536
#define DT_RANK   48
#define BATCH     4
#define SEQ_LEN   2048
#define BL        (BATCH * SEQ_LEN)        // 8192 rows
#define NCHUNK    32
#define CHUNK     (SEQ_LEN / NCHUNK)       // 64

typedef __bf16 bf16x8 __attribute__((ext_vector_type(8)));
typedef float  f32x4  __attribute__((ext_vector_type(4)));

__device__ __forceinline__ void async_copy16(const void* g, void* l) {
    __builtin_amdgcn_global_load_lds(
        (const __attribute__((address_space(1))) void*)g,
        (__attribute__((address_space(3))) void*)l,
        16, 0, 0);
}

// ---------------------------------------------------------------------------
// In-proj split-bf16 MFMA GEMM (NT), BK=64 (R8: halves barrier count vs BK=32;
// the vmcnt(0) drain before s_barrier is the structural ~20% stall).
// A: M x 2K [hi|lo], B: N x 2K [hi|lo]; C = Ah*Bh + Ah*Bl + Al*Bh via three
// contiguous K sub-loops. 128x128 tile, 4 waves of 64x64. K % 64 == 0.
// LDS rows are 128B (8 chunks of 16B); chunk q of row r stored at slot
// q ^ (r&7) (swizzle applied on the global-source side; staging instrs stay
// 1024B-contiguous per the global_load_lds lane*16 rule).
// ---------------------------------------------------------------------------
__global__ __launch_bounds__(256)
void gemm_in(const __bf16* __restrict__ A, const __bf16* __restrict__ B,
             float* __restrict__ C, int M, int N, int K, int ldc)
{
    __shared__ __bf16 Asl[128 * 64];
    __shared__ __bf16 Bsl[128 * 64];

    const int tid  = threadIdx.x;
    const int lane = tid & 63;
    const int w    = tid >> 6;
    const int wm   = (w >> 1) * 64;
    const int wn   = (w & 1) * 64;

    const int bm = blockIdx.y * 128;
    const int bn = blockIdx.x * 128;

    const long lda = 2L * K;
    const long ldb = 2L * K;

    f32x4 acc[4][4];
    #pragma unroll
    for (int i = 0; i < 4; ++i)
        #pragma unroll
        for (int j = 0; j < 4; ++j)
            acc[i][j] = (f32x4){0.f, 0.f, 0.f, 0.f};

    // staging: lane l -> row w*32 + (l>>3), global chunk (l&7)^((l>>3)&7);
    // 4 instrs per operand cover rows +0/+8/+16/+24.
    const int srow = w * 32 + (lane >> 3);
    const int kc8  = ((lane & 7) ^ ((lane >> 3) & 7)) * 8;
    const __bf16* Abase = A + (long)(bm + srow) * lda + kc8;
    const __bf16* Bbase = B + (long)(bn + srow) * ldb + kc8;
    char* AslW = (char*)Asl + (w * 32) * 128;
    char* BslW = (char*)Bsl + (w * 32) * 128;

    const int fr = lane & 15;
    const int g4 = lane >> 4;          // 0..3 (k-chunk group within a k-step)
    const long lda8 = 8 * lda, ldb8 = 8 * ldb;

    const int aoff[3] = {0, 0, K};
    const int boff[3] = {0, K, 0};

    #pragma unroll
    for (int s = 0; s < 3; ++s) {
        const __bf16* Ab = Abase + aoff[s];
        const __bf16* Bb = Bbase + boff[s];
        for (int kk = 0; kk < K; kk += 64) {
            __syncthreads();
            #pragma unroll
            for (int j = 0; j < 4; ++j) {
                async_copy16(Ab + j * lda8 + kk, AslW + j * 1024);
                async_copy16(Bb + j * ldb8 + kk, BslW + j * 1024);
            }
            __syncthreads();

            #pragma unroll
            for (int ks = 0; ks < 2; ++ks) {
                const int c = ks * 4 + g4;     // wanted 16B chunk 0..7
                bf16x8 af[4], bfr[4];
                #pragma unroll
                for (int t = 0; t < 4; ++t) {
                    const int ra = wm + t * 16 + fr;
                    const int rb = wn + t * 16 + fr;
                    af[t]  = *(const bf16x8*)&Asl[ra * 64 + ((c ^ (ra & 7)) * 8)];
                    bfr[t] = *(const bf16x8*)&Bsl[rb * 64 + ((c ^ (rb & 7)) * 8)];
                }
                #pragma unroll
                for (int i = 0; i < 4; ++i)
                    #pragma unroll
                    for (int j = 0; j < 4; ++j)
                        acc[i][j] = __builtin_amdgcn_mfma_f32_16x16x32_bf16(af[i], bfr[j], acc[i][j], 0, 0, 0);
            }
        }
    }

    // C/D layout (m89-verified): col = lane&15, row = (lane>>4)*4 + reg
    const int cn  = lane & 15;
    const int cr4 = (lane >> 4) * 4;
    #pragma unroll
    for (int i = 0; i < 4; ++i)
        #pragma unroll
        for (int j = 0; j < 4; ++j)
            #pragma unroll
            for (int r = 0; r < 4; ++r) {
                const int row = bm + wm + i * 16 + cr4 + r;
                const int col = bn + wn + j * 16 + cn;
                C[(long)row * ldc + col] = acc[i][j][r];
            }
}

// ---------------------------------------------------------------------------
// Out-proj split-bf16 MFMA GEMM (NT), BM=128 x BN=64, BK=32 (R8: grid 12x64 =
// 768 blocks = even 3 blocks/CU; old BN=128 gave 384 = 1.5/CU imbalance).
// Wave w covers rows w*32..+32, all 64 cols. R7 64B-row layout + swizzle.
// ---------------------------------------------------------------------------
__global__ __launch_bounds__(256)
void gemm_out64(const __bf16* __restrict__ A, const __bf16* __restrict__ B,
                float* __restrict__ C, int M, int N, int K, int ldc)
{
    __shared__ __bf16 Asl[128 * 32];
    __shared__ __bf16 Bsl[64 * 32];

    const int tid  = threadIdx.x;
    const int lane = tid & 63;
    const int w    = tid >> 6;
    const int wm   = w * 32;

    const int bm = blockIdx.y * 128;
    const int bn = blockIdx.x * 64;

    const long lda = 2L * K;
    const long ldb = 2L * K;

    f32x4 acc[2][4];
    #pragma unroll
    for (int i = 0; i < 2; ++i)
        #pragma unroll
        for (int j = 0; j < 4; ++j)
            acc[i][j] = (f32x4){0.f, 0.f, 0.f, 0.f};

    const int kc8   = ((lane & 3) ^ ((lane >> 2) & 3)) * 8;
    const int srowA = w * 32 + (lane >> 2);
    const int srowB = w * 16 + (lane >> 2);
    const __bf16* Abase = A + (long)(bm + srowA) * lda + kc8;
    const __bf16* Bbase = B + (long)(bn + srowB) * ldb + kc8;
    char* AslW = (char*)Asl + (w * 32) * 64;
    char* BslW = (char*)Bsl + (w * 16) * 64;

    const int fr    = lane & 15;
    const int slotK = ((lane >> 4) ^ (fr & 3)) * 8;   // slot recovers chunk lane>>4
    const long lda16 = 16 * lda, ldb16 = 16 * ldb;

    const int aoff[3] = {0, 0, K};
    const int boff[3] = {0, K, 0};

    #pragma unroll
    for (int s = 0; s < 3; ++s) {
        const __bf16* Ab = Abase + aoff[s];
        const __bf16* Bb = Bbase + boff[s];
        for (int kk = 0; kk < K; kk += 32) {
            __syncthreads();
            async_copy16(Ab + kk,         AslW);
            async_copy16(Ab + lda16 + kk, AslW + 16 * 64);
            async_copy16(Bb + kk,         BslW);
            __syncthreads();

            bf16x8 af[2], bfr[4];
            #pragma unroll
            for (int t = 0; t < 2; ++t)
                af[t] = *(const bf16x8*)&Asl[(wm + t * 16 + fr) * 32 + slotK];
            #pragma unroll
            for (int t = 0; t < 4; ++t)
                bfr[t] = *(const bf16x8*)&Bsl[(t * 16 + fr) * 32 + slotK];
            #pragma unroll
            for (int i = 0; i < 2; ++i)
                #pragma unroll
                for (int j = 0; j < 4; ++j)
                    acc[i][j] = __builtin_amdgcn_mfma_f32_16x16x32_bf16(af[i], bfr[j], acc[i][j], 0, 0, 0);
        }
    }

    const int cn  = lane & 15;
    const int cr4 = (lane >> 4) * 4;
    #pragma unroll
    for (int i = 0; i < 2; ++i)
        #pragma unroll
        for (int j = 0; j < 4; ++j)
            #pragma unroll
            for (int r = 0; r < 4; ++r) {
                const int row = bm + wm + i * 16 + cr4 + r;
                const int col = bn + j * 16 + cn;
                C[(long)row * ldc + col] = acc[i][j][r];
            }
}

// ---------------------------------------------------------------------------
// x_dbl split-K MFMA GEMM (unchanged from R7): A = xcS, B = W_xS (128-row
// padded, 80 valid), K'=4608 -> 144 k-tiles split 4. Pout[s][8192][128].
// ---------------------------------------------------------------------------
__global__ __launch_bounds__(256)
void gemm_xdbl(const __bf16* __restrict__ A, const __bf16* __restrict__ B,
               float* __restrict__ Pout)
{
    __shared__ __bf16 Asl[128 * 32];
    __shared__ __bf16 Bsl[128 * 32];

    const int tid  = threadIdx.x;
    const int lane = tid & 63;
    const int w    = tid >> 6;
    const int wm   = (w >> 1) * 64;
    const int wn   = (w & 1) * 64;

    const int s  = blockIdx.x;
    const int bm = blockIdx.y * 128;
    const long lda = 3072, ldb = 3072;
    const int K = 1536;

    f32x4 acc[4][4];
    #pragma unroll
    for (int i = 0; i < 4; ++i)
        #pragma unroll
        for (int j = 0; j < 4; ++j)
            acc[i][j] = (f32x4){0.f, 0.f, 0.f, 0.f};

    const int srow = w * 32 + (lane >> 2);
    const int kc8  = (((lane & 3) ^ ((lane >> 2) & 3))) * 8;
    const __bf16* Abase = A + (long)(bm + srow) * lda + kc8;
    const __bf16* Bbase = B + (long)srow * ldb + kc8;
    char* AslW = (char*)Asl + (w * 32) * 64;
    char* BslW = (char*)Bsl + (w * 32) * 64;

    const int rdK = (((lane >> 4) ^ (lane & 3))) * 8;
    const int fr  = lane & 15;
    const long lda16 = 16 * lda, ldb16 = 16 * ldb;

    const int aoff[3] = {0, 0, K};
    const int boff[3] = {0, K, 0};
    const int kt0 = s * 36, kt1 = kt0 + 36;

    #pragma unroll
    for (int seg = 0; seg < 3; ++seg) {
        const int lo  = (kt0 > seg * 48)      ? kt0 : seg * 48;
        const int hiE = (kt1 < seg * 48 + 48) ? kt1 : seg * 48 + 48;
        const __bf16* Ab = Abase + aoff[seg];
        const __bf16* Bb = Bbase + boff[seg];
        for (int kt = lo; kt < hiE; ++kt) {
            const int kk = (kt - seg * 48) * 32;
            __syncthreads();
            async_copy16(Ab + kk,         AslW);
            async_copy16(Ab + lda16 + kk, AslW + 16 * 64);
            async_copy16(Bb + kk,         BslW);
            async_copy16(Bb + ldb16 + kk, BslW + 16 * 64);
            __syncthreads();

            bf16x8 af[4], bfr[4];
            #pragma unroll
            for (int t = 0; t < 4; ++t) {
                af[t]  = *(const bf16x8*)&Asl[(wm + t * 16 + fr) * 32 + rdK];
                bfr[t] = *(const bf16x8*)&Bsl[(wn + t * 16 + fr) * 32 + rdK];
            }
            #pragma unroll
            for (int i = 0; i < 4; ++i)
                #pragma unroll
                for (int j = 0; j < 4; ++j)
                    acc[i][j] = __builtin_amdgcn_mfma_f32_16x16x32_bf16(af[i], bfr[j], acc[i][j], 0, 0, 0);
        }
    }

    float* Cp = Pout + (long)s * (8192L * 128);
    const int cn  = lane & 15;
    const int cr4 = (lane >> 4) * 4;
    #pragma unroll
    for (int i = 0; i < 4; ++i)
        #pragma unroll
        for (int j = 0; j < 4; ++j)
            #pragma unroll
            for (int r = 0; r < 4; ++r) {
                const int row = bm + wm + i * 16 + cr4 + r;
                const int col = wn + j * 16 + cn;
                Cp[(long)row * 128 + col] = acc[i][j][r];
            }
}

// ---------------------------------------------------------------------------
// dt_fused (R8): one kernel replaces xdbl_reduce2 + dt-GEMM.
// Stages A = split(reduce4(Pout)[:, 0:48], pad 64) and B = split(W_dt, pad 64)
// into LDS ONCE (manual ds stores; padded stride 136 for bank spread), then
// runs 3x2 k-tiles of MFMA and the softplus+bias epilogue into xz cols 0..1535.
// bn==0 blocks also emit xbc = reduce4(Pout)[:, 48:80] (B/C for the scan).
// ---------------------------------------------------------------------------
#define DT_LD 136
__global__ __launch_bounds__(256)
void dt_fused(const float* __restrict__ Pout, const float* __restrict__ W_dt,
              const float* __restrict__ b_dt, float* __restrict__ xz,
              float* __restrict__ xbc)
{
    __shared__ __bf16 Asl[128 * DT_LD];
    __shared__ __bf16 Bsl[128 * DT_LD];

    const int tid  = threadIdx.x;
    const int lane = tid & 63;
    const int w    = tid >> 6;
    const int wm   = (w >> 1) * 64;
    const int wn   = (w & 1) * 64;

    const int bn = blockIdx.x;       // 0..11  (col block of 128 over N=1536)
    const int bm = blockIdx.y;       // 0..63  (row block of 128 over M=8192)
    const long st = 8192L * 128;
    const long arow0 = (long)bm * 128;

    // stage A: value(r,k) = sum_s Pout[s][bm*128+r][k] for k<48, else 0
    #pragma unroll 4
    for (int u = 0; u < 32; ++u) {
        const int idx = u * 256 + tid;        // 0..8191 over 128x64
        const int r = idx >> 6, k = idx & 63;
        float v = 0.f;
        if (k < 48) {
            const long o = (arow0 + r) * 128 + k;
            v = (Pout[o] + Pout[o + st]) + (Pout[o + 2 * st] + Pout[o + 3 * st]);
        }
        const __bf16 hi = (__bf16)v;
        Asl[r * DT_LD + k]      = hi;
        Asl[r * DT_LD + 64 + k] = (__bf16)(v - (float)hi);
    }
    // stage B: W_dt rows bn*128..+128, k<48 else 0
    #pragma unroll 4
    for (int u = 0; u < 32; ++u) {
        const int idx = u * 256 + tid;
        const int r = idx >> 6, k = idx & 63;
        float v = (k < 48) ? W_dt[(bn * 128 + r) * 48 + k] : 0.f;
        const __bf16 hi = (__bf16)v;
        Bsl[r * DT_LD + k]      = hi;
        Bsl[r * DT_LD + 64 + k] = (__bf16)(v - (float)hi);
    }
    // xbc (cols 48..79 of the reduce) emitted once, by bn==0 blocks
    if (bn == 0) {
        #pragma unroll 4
        for (int u = 0; u < 16; ++u) {
            const int idx = u * 256 + tid;    // 0..4095 over 128x32
            const int r = idx >> 5, j = idx & 31;
            const long o = (arow0 + r) * 128 + 48 + j;
            xbc[(arow0 + r) * 32 + j] =
                (Pout[o] + Pout[o + st]) + (Pout[o + 2 * st] + Pout[o + 3 * st]);
        }
    }
    __syncthreads();

    f32x4 acc[4][4];
    #pragma unroll
    for (int i = 0; i < 4; ++i)
        #pragma unroll
        for (int j = 0; j < 4; ++j)
            acc[i][j] = (f32x4){0.f, 0.f, 0.f, 0.f};

    const int fr = lane & 15;
    const int k8 = (lane >> 4) * 8;
    const int aoff[3] = {0, 0, 64};
    const int boff[3] = {0, 64, 0};
    #pragma unroll
    for (int s = 0; s < 3; ++s)
        #pragma unroll
        for (int kk = 0; kk < 64; kk += 32) {
            bf16x8 af[4], bfr[4];
            #pragma unroll
            for (int t = 0; t < 4; ++t) {
                af[t]  = *(const bf16x8*)&Asl[(wm + t * 16 + fr) * DT_LD + aoff[s] + kk + k8];
                bfr[t] = *(const bf16x8*)&Bsl[(wn + t * 16 + fr) * DT_LD + boff[s] + kk + k8];
            }
            #pragma unroll
            for (int i = 0; i < 4; ++i)
                #pragma unroll
                for (int j = 0; j < 4; ++j)
                    acc[i][j] = __builtin_amdgcn_mfma_f32_16x16x32_bf16(af[i], bfr[j], acc[i][j], 0, 0, 0);
        }

    const int cn  = lane & 15;
    const int cr4 = (lane >> 4) * 4;
    #pragma unroll
    for (int i = 0; i < 4; ++i)
        #pragma unroll
        for (int j = 0; j < 4; ++j)
            #pragma unroll
            for (int r = 0; r < 4; ++r) {
                const int row = bm * 128 + wm + i * 16 + cr4 + r;
                const int col = bn * 128 + wn + j * 16 + cn;
                float v = acc[i][j][r] + b_dt[col];
                v = fmaxf(v, 0.f) + log1pf(__expf(-fabsf(v)));   // stable softplus
                xz[(long)row * 3072 + col] = v;
            }
}

// ---------------------------------------------------------------------------
// Merged input/weight split: x, W_in, W_out, W_x  (W_dt handled by dt_fused).
// ---------------------------------------------------------------------------
#define NW0 ((long)BL * 768)
#define NW1 (3072L * 768)
#define NW2 (768L * 1536)
#define NW3 (80L * 1536)
__global__ __launch_bounds__(256)
void split_all(const float* __restrict__ x,
               const float* __restrict__ W_in, const float* __restrict__ W_out,
               const float* __restrict__ W_x,
               __bf16* __restrict__ xS,
               __bf16* __restrict__ wInS, __bf16* __restrict__ wOutS,
               __bf16* __restrict__ wXS)
{
    long i = (long)blockIdx.x * 256 + threadIdx.x;
    if (i < NW0) {
        const long row = i / 768; const int col = (int)(i - row * 768);
        const float a = x[i];
        const __bf16 h = (__bf16)a;
        __bf16* d = xS + row * 1536 + col;
        d[0] = h; d[768] = (__bf16)(a - (float)h);
        return;
    }
    i -= NW0;
    if (i < NW1) {
        const long row = i / 768; const int col = (int)(i - row * 768);
        const float a = W_in[i];
        const __bf16 h = (__bf16)a;
        __bf16* d = wInS + row * 1536 + col;
        d[0] = h; d[768] = (__bf16)(a - (float)h);
        return;
    }
    i -= NW1;
    if (i < NW2) {
        const long row = i / 1536; const int col = (int)(i - row * 1536);
        const float a = W_out[i];
        const __bf16 h = (__bf16)a;
        __bf16* d = wOutS + row * 3072 + col;
        d[0] = h; d[1536] = (__bf16)(a - (float)h);
        return;
    }
    i -= NW2;
    if (i < NW3) {
        const long row = i / 1536; const int col = (int)(i - row * 1536);
        const float a = W_x[i];
        const __bf16 h = (__bf16)a;
        __bf16* d = wXS + row * 3072 + col;
        d[0] = h; d[1536] = (__bf16)(a - (float)h);
    }
}

// ---------------------------------------------------------------------------
// Depthwise causal conv (width 4) + bias + SiLU -> xcS split-bf16.
// ---------------------------------------------------------------------------
__global__ __launch_bounds__(256)
void conv_silu_kernel(const float* __restrict__ xz,
                      const float* __restrict__ conv_w,
                      const float* __restrict__ conv_b,
                      __bf16* __restrict__ xcS)
{
    const long idx = (long)blockIdx.x * 256 + threadIdx.x;
    const int d  = (int)(idx % D_INNER);
    const long bl = idx / D_INNER;
    const int l  = (int)(bl % SEQ_LEN);

    const float w0 = conv_w[d * 4 + 0];
    const float w1 = conv_w[d * 4 + 1];
    const float w2 = conv_w[d * 4 + 2];
    const float w3 = conv_w[d * 4 + 3];

    const float* base = xz + bl * 3072 + d;
    float s = conv_b[d];
    if (l >= 3) s = fmaf(base[-3 * 3072], w0, s);
    if (l >= 2) s = fmaf(base[-2 * 3072], w1, s);
    if (l >= 1) s = fmaf(base[-1 * 3072], w2, s);
    s = fmaf(base[0], w3, s);
    const float sig = 1.f / (1.f + __expf(-s));
    const float v = s * sig;
    const __bf16 hi = (__bf16)v;
    const __bf16 lo = (__bf16)(v - (float)hi);
    xcS[bl * 3072 + d]        = hi;
    xcS[bl * 3072 + 1536 + d] = lo;
}

// ---------------------------------------------------------------------------
// Scan phase A: per (b, d, chunk): P = prod(a_l), S = local scan (h0=0).
// B/C now read from xbc (8192 x 32: B_t = [0:16], C_t = [16:32]).
// ---------------------------------------------------------------------------
__global__ __launch_bounds__(256)
void scan_phaseA(const __bf16* __restrict__ xcS, const float* __restrict__ xz,
                 const float* __restrict__ xbc, const float* __restrict__ A_log,
                 float* __restrict__ P, float* __restrict__ S)
{
    const int d = blockIdx.x * 256 + threadIdx.x;
    const int c = blockIdx.y;
    const int b = blockIdx.z;

    float An[16], Pr[16], Sr[16];
    #pragma unroll
    for (int n = 0; n < 16; ++n) {
        An[n] = -__expf(A_log[d * 16 + n]);
        Pr[n] = 1.f;
        Sr[n] = 0.f;
    }

    const long bl0 = (long)b * SEQ_LEN + (long)c * CHUNK;
    for (int l = 0; l < CHUNK; ++l) {
        const long bl = bl0 + l;
        const float dt  = xz[bl * 3072 + d];
        const float x   = (float)xcS[bl * 3072 + d] + (float)xcS[bl * 3072 + 1536 + d];
        const float dtx = dt * x;
        const float* bc = xbc + bl * 32;
        #pragma unroll
        for (int n = 0; n < 16; ++n) {
            const float a = __expf(dt * An[n]);
            Pr[n] *= a;
            Sr[n] = fmaf(a, Sr[n], dtx * bc[n]);
        }
    }

    const long base = ((long)(b * NCHUNK + c) * 16) * D_INNER + d;
    #pragma unroll
    for (int n = 0; n < 16; ++n) {
        P[base + (long)n * D_INNER] = Pr[n];
        S[base + (long)n * D_INNER] = Sr[n];
    }
}

// ---------------------------------------------------------------------------
// Scan phase B: sequential chunk-combine per (b, d): H[c] = h_in for chunk c.
// ---------------------------------------------------------------------------
__global__ __launch_bounds__(256)
void scan_phaseB(const float* __restrict__ P, const float* __restrict__ S,
                 float* __restrict__ H)
{
    const int t = blockIdx.x * 256 + threadIdx.x;
    const int d = t % D_INNER;
    const int b = t / D_INNER;

    float h[16];
    #pragma unroll
    for (int n = 0; n < 16; ++n) h[n] = 0.f;

    for (int c = 0; c < NCHUNK; ++c) {
        const long base = ((long)(b * NCHUNK + c) * 16) * D_INNER + d;
        #pragma unroll
        for (int n = 0; n < 16; ++n) {
            const long i = base + (long)n * D_INNER;
            H[i] = h[n];
            h[n] = fmaf(P[i], h[n], S[i]);
        }
    }
}

// ---------------------------------------------------------------------------
// Scan phase C: re-run chunks from h_in, emit y, gate with silu(z), write
// split-bf16 in-place over xcS -> yS.
// ---------------------------------------------------------------------------
__global__ __launch_bounds__(256)
void scan_phaseC(__bf16* xcS_yS, const float* __restrict__ xz,
                 const float* __restrict__ xbc, const float* __restrict__ A_log,
                 const float* __restrict__ Dp, const float* __restrict__ H)
{
    const int d = blockIdx.x * 256 + threadIdx.x;
    const int c = blockIdx.y;
    const int b = blockIdx.z;

    float An[16], h[16];
    const long hbase = ((long)(b * NCHUNK + c) * 16) * D_INNER + d;
    #pragma unroll
    for (int n = 0; n < 16; ++n) {
        An[n] = -__expf(A_log[d * 16 + n]);
        h[n]  = H[hbase + (long)n * D_INNER];
    }
    const float Dd = Dp[d];

    const long bl0 = (long)b * SEQ_LEN + (long)c * CHUNK;
    for (int l = 0; l < CHUNK; ++l) {
        const long bl = bl0 + l;
        const float dt  = xz[bl * 3072 + d];
        const float x   = (float)xcS_yS[bl * 3072 + d] + (float)xcS_yS[bl * 3072 + 1536 + d];
        const float dtx = dt * x;
        const float* bc = xbc + bl * 32;
        float y = Dd * x;
        #pragma unroll
        for (int n = 0; n < 16; ++n) {
            const float a = __expf(dt * An[n]);
            h[n] = fmaf(a, h[n], dtx * bc[n]);
            y = fmaf(h[n], bc[16 + n], y);
        }
        const float z  = xz[bl * 3072 + D_INNER + d];
        const float sz = z / (1.f + __expf(-z));
        const float v  = y * sz;
        const __bf16 hi = (__bf16)v;
        const __bf16 lo = (__bf16)(v - (float)hi);
        xcS_yS[bl * 3072 + d]        = hi;
        xcS_yS[bl * 3072 + 1536 + d] = lo;
    }
}

// ---------------------------------------------------------------------------
extern "C" void kernel_launch(void* const* d_in, const int* in_sizes, int n_in,
                              void* d_out, int out_size, void* d_ws, size_t ws_size,
                              hipStream_t stream)
{
    const float* x      = (const float*)d_in[0];   // (4,2048,768)
    const float* W_in   = (const float*)d_in[1];   // (3072,768)
    const float* conv_w = (const float*)d_in[2];   // (1536,1,4)
    const float* conv_b = (const float*)d_in[3];   // (1536,)
    const float* W_x    = (const float*)d_in[4];   // (80,1536)
    const float* W_dt   = (const float*)d_in[5];   // (1536,48)
    const float* b_dt   = (const float*)d_in[6];   // (1536,)
    const float* A_log  = (const float*)d_in[7];   // (1536,16)
    const float* D_p    = (const float*)d_in[8];   // (1536,)
    const float* W_out  = (const float*)d_in[9];   // (768,1536)
    float* out = (float*)d_out;                    // (4,2048,768)

    // ---- workspace carve, ~200 MB ---------------------------------------
    char* p = (char*)d_ws;
    auto take = [&](size_t bytes) { char* r = p; p += (bytes + 255) & ~(size_t)255; return r; };

    float*  xz    = (float*)take((size_t)BL * 3072 * 4);    // 100.7 MB (dt | z)
    float*  H     = (float*)take((size_t)BATCH * NCHUNK * 16 * D_INNER * 4); // 12.6 MB
    __bf16* wOutS = (__bf16*)take(768L * 3072 * 2);         //   4.7 MB
    __bf16* wXS   = (__bf16*)take(128L * 3072 * 2);         //   0.8 MB (80 valid)
    float*  xbc   = (float*)take(8192L * 32 * 4);           //   1.0 MB
    float*  Pout  = (float*)take(4L * 8192 * 128 * 4);      //  16.8 MB (-> P overlay)
    float*  S     = (float*)take((size_t)BATCH * NCHUNK * 16 * D_INNER * 4); // 12.6 MB
    float*  P     = Pout;   // Pout dead after dt_fused; P needs 12.6 MB

    // REGION (50.4 MB), time-multiplexed:
    //   phase 1:   xS (25.2MB) + wInS (9.4MB)
    //   phase 2-8: xcS (8192x3072 bf16), phaseC overwrites in-place -> yS
    char* region = take(50331648);
    __bf16* xS   = (__bf16*)region;
    __bf16* wInS = (__bf16*)(region + 25165824);
    __bf16* xcS  = (__bf16*)region;
    __bf16* yS   = (__bf16*)region;

    // 0) split conversions (x + weights, one launch)
    {
        const long n = NW0 + NW1 + NW2 + NW3;
        split_all<<<(int)((n + 255) / 256), 256, 0, stream>>>(
            x, W_in, W_out, W_x, xS, wInS, wOutS, wXS);
    }
    // 1) xz = x @ W_in^T  (BK=64 MFMA, M=8192, N=3072, K=768)
    {
        dim3 grid(3072 / 128, BL / 128);
        gemm_in<<<grid, 256, 0, stream>>>(xS, wInS, xz, BL, 3072, 768, 3072);
    }
    // 2) conv + bias + SiLU -> xcS (overlays xS)
    {
        const long total = (long)BL * D_INNER;
        conv_silu_kernel<<<(int)(total / 256), 256, 0, stream>>>(xz, conv_w, conv_b, xcS);
    }
    // 3) x_dbl split-K MFMA -> Pout
    {
        dim3 grid(4, BL / 128);
        gemm_xdbl<<<grid, 256, 0, stream>>>(xcS, wXS, Pout);
    }
    // 4) dt_fused: reduce(Pout) -> dt GEMM (softplus) -> xz cols 0..1535; + xbc
    {
        dim3 grid(12, 64);
        dt_fused<<<grid, 256, 0, stream>>>(Pout, W_dt, b_dt, xz, xbc);
    }
    // 5) scan phase A  (P overlays dead Pout)
    {
        dim3 grid(D_INNER / 256, NCHUNK, BATCH);
        scan_phaseA<<<grid, 256, 0, stream>>>(xcS, xz, xbc, A_log, P, S);
    }
    // 6) scan phase B
    scan_phaseB<<<(BATCH * D_INNER) / 256, 256, 0, stream>>>(P, S, H);
    // 7) scan phase C: xcS -> yS in-place
    {
        dim3 grid(D_INNER / 256, NCHUNK, BATCH);
        scan_phaseC<<<grid, 256, 0, stream>>>(xcS, xz, xbc, A_log, D_p, H);
    }
    // 8) out = y @ W_out^T  (BN=64 MFMA, M=8192, N=768, K=1536)
    {
        dim3 grid(768 / 64, BL / 128);
        gemm_out64<<<grid, 256, 0, stream>>>(yS, wOutS, out, BL, 768, 1536, 768);
    }
}

// Round 9
// 571.937 us; speedup vs baseline: 1.2274x; 1.2274x over previous
//
#include <hip/hip_runtime.h>
#include <hip/hip_bf16.h>
#include <math.h>

// Problem constants (fixed by reference)
#define D_MODEL   768
#define D_STATE   16
#define D_CONV    4
#define D_INNER   1536
#define DT_RANK   48
#define BATCH     4
#define SEQ_LEN   2048
#define BL        (BATCH * SEQ_LEN)        // 8192 rows
#define NCHUNK    32
#define CHUNK     (SEQ_LEN / NCHUNK)       // 64

typedef __bf16 bf16x8 __attribute__((ext_vector_type(8)));
typedef float  f32x4  __attribute__((ext_vector_type(4)));

__device__ __forceinline__ void async_copy16(const void* g, void* l) {
    __builtin_amdgcn_global_load_lds(
        (const __attribute__((address_space(1))) void*)g,
        (__attribute__((address_space(3))) void*)l,
        16, 0, 0);
}

// ---------------------------------------------------------------------------
// Split-bf16 MFMA GEMM (NT), BK=64 (R8-verified: 148 us on in-proj, conflicts
// 0, MfmaUtil 35). A: M x 2K [hi|lo], B: N x 2K [hi|lo];
// C = Ah*Bh + Ah*Bl + Al*Bh via three contiguous K sub-loops.
// 128x128 tile, 4 waves of 64x64. K % 64 == 0.
// LDS rows 128B (8 chunks of 16B); chunk q of row r at slot q ^ (r&7)
// (swizzle on the global-source side; staging stays 1024B-contiguous).
// EPI 0: plain store.  EPI 1: softplus(v + bias[col]) (dt epilogue).
// Used for in-proj, dt (K=64 padded), out-proj (R8's BN=64 + dt_fused both
// regressed: 12x A re-reads / 69.6KB LDS + 12x redundant reduce — reverted).
// ---------------------------------------------------------------------------
template <int EPI>
__global__ __launch_bounds__(256)
void gemm_in(const __bf16* __restrict__ A, const __bf16* __restrict__ B,
             float* __restrict__ C, const float* __restrict__ bias,
             int M, int N, int K, int ldc)
{
    __shared__ __bf16 Asl[128 * 64];
    __shared__ __bf16 Bsl[128 * 64];

    const int tid  = threadIdx.x;
    const int lane = tid & 63;
    const int w    = tid >> 6;
    const int wm   = (w >> 1) * 64;
    const int wn   = (w & 1) * 64;

    const int bm = blockIdx.y * 128;
    const int bn = blockIdx.x * 128;

    const long lda = 2L * K;
    const long ldb = 2L * K;

    f32x4 acc[4][4];
    #pragma unroll
    for (int i = 0; i < 4; ++i)
        #pragma unroll
        for (int j = 0; j < 4; ++j)
            acc[i][j] = (f32x4){0.f, 0.f, 0.f, 0.f};

    // staging: lane l -> row w*32 + (l>>3), global chunk (l&7)^((l>>3)&7);
    // 4 instrs per operand cover rows +0/+8/+16/+24.
    const int srow = w * 32 + (lane >> 3);
    const int kc8  = ((lane & 7) ^ ((lane >> 3) & 7)) * 8;
    const __bf16* Abase = A + (long)(bm + srow) * lda + kc8;
    const __bf16* Bbase = B + (long)(bn + srow) * ldb + kc8;
    char* AslW = (char*)Asl + (w * 32) * 128;
    char* BslW = (char*)Bsl + (w * 32) * 128;

    const int fr = lane & 15;
    const int g4 = lane >> 4;          // 0..3 (k-chunk group within a k-step)
    const long lda8 = 8 * lda, ldb8 = 8 * ldb;

    const int aoff[3] = {0, 0, K};
    const int boff[3] = {0, K, 0};

    #pragma unroll
    for (int s = 0; s < 3; ++s) {
        const __bf16* Ab = Abase + aoff[s];
        const __bf16* Bb = Bbase + boff[s];
        for (int kk = 0; kk < K; kk += 64) {
            __syncthreads();
            #pragma unroll
            for (int j = 0; j < 4; ++j) {
                async_copy16(Ab + j * lda8 + kk, AslW + j * 1024);
                async_copy16(Bb + j * ldb8 + kk, BslW + j * 1024);
            }
            __syncthreads();

            #pragma unroll
            for (int ks = 0; ks < 2; ++ks) {
                const int c = ks * 4 + g4;     // wanted 16B chunk 0..7
                bf16x8 af[4], bfr[4];
                #pragma unroll
                for (int t = 0; t < 4; ++t) {
                    const int ra = wm + t * 16 + fr;
                    const int rb = wn + t * 16 + fr;
                    af[t]  = *(const bf16x8*)&Asl[ra * 64 + ((c ^ (ra & 7)) * 8)];
                    bfr[t] = *(const bf16x8*)&Bsl[rb * 64 + ((c ^ (rb & 7)) * 8)];
                }
                #pragma unroll
                for (int i = 0; i < 4; ++i)
                    #pragma unroll
                    for (int j = 0; j < 4; ++j)
                        acc[i][j] = __builtin_amdgcn_mfma_f32_16x16x32_bf16(af[i], bfr[j], acc[i][j], 0, 0, 0);
            }
        }
    }

    // C/D layout (m89-verified): col = lane&15, row = (lane>>4)*4 + reg
    const int cn  = lane & 15;
    const int cr4 = (lane >> 4) * 4;
    #pragma unroll
    for (int i = 0; i < 4; ++i)
        #pragma unroll
        for (int j = 0; j < 4; ++j)
            #pragma unroll
            for (int r = 0; r < 4; ++r) {
                const int row = bm + wm + i * 16 + cr4 + r;
                const int col = bn + wn + j * 16 + cn;
                float v = acc[i][j][r];
                if (EPI == 1) {
                    v += bias[col];
                    v = fmaxf(v, 0.f) + log1pf(__expf(-fabsf(v)));  // stable softplus
                }
                C[(long)row * ldc + col] = v;
            }
}

// ---------------------------------------------------------------------------
// x_dbl split-K MFMA GEMM (R7 structure): A = xcS, B = W_xS (128-row padded,
// 80 valid), K'=4608 -> 144 k-tiles split 4. Pout[s][8192][128].
// ---------------------------------------------------------------------------
__global__ __launch_bounds__(256)
void gemm_xdbl(const __bf16* __restrict__ A, const __bf16* __restrict__ B,
               float* __restrict__ Pout)
{
    __shared__ __bf16 Asl[128 * 32];
    __shared__ __bf16 Bsl[128 * 32];

    const int tid  = threadIdx.x;
    const int lane = tid & 63;
    const int w    = tid >> 6;
    const int wm   = (w >> 1) * 64;
    const int wn   = (w & 1) * 64;

    const int s  = blockIdx.x;
    const int bm = blockIdx.y * 128;
    const long lda = 3072, ldb = 3072;
    const int K = 1536;

    f32x4 acc[4][4];
    #pragma unroll
    for (int i = 0; i < 4; ++i)
        #pragma unroll
        for (int j = 0; j < 4; ++j)
            acc[i][j] = (f32x4){0.f, 0.f, 0.f, 0.f};

    const int srow = w * 32 + (lane >> 2);
    const int kc8  = (((lane & 3) ^ ((lane >> 2) & 3))) * 8;
    const __bf16* Abase = A + (long)(bm + srow) * lda + kc8;
    const __bf16* Bbase = B + (long)srow * ldb + kc8;
    char* AslW = (char*)Asl + (w * 32) * 64;
    char* BslW = (char*)Bsl + (w * 32) * 64;

    const int rdK = (((lane >> 4) ^ (lane & 3))) * 8;
    const int fr  = lane & 15;
    const long lda16 = 16 * lda, ldb16 = 16 * ldb;

    const int aoff[3] = {0, 0, K};
    const int boff[3] = {0, K, 0};
    const int kt0 = s * 36, kt1 = kt0 + 36;

    #pragma unroll
    for (int seg = 0; seg < 3; ++seg) {
        const int lo  = (kt0 > seg * 48)      ? kt0 : seg * 48;
        const int hiE = (kt1 < seg * 48 + 48) ? kt1 : seg * 48 + 48;
        const __bf16* Ab = Abase + aoff[seg];
        const __bf16* Bb = Bbase + boff[seg];
        for (int kt = lo; kt < hiE; ++kt) {
            const int kk = (kt - seg * 48) * 32;
            __syncthreads();
            async_copy16(Ab + kk,         AslW);
            async_copy16(Ab + lda16 + kk, AslW + 16 * 64);
            async_copy16(Bb + kk,         BslW);
            async_copy16(Bb + ldb16 + kk, BslW + 16 * 64);
            __syncthreads();

            bf16x8 af[4], bfr[4];
            #pragma unroll
            for (int t = 0; t < 4; ++t) {
                af[t]  = *(const bf16x8*)&Asl[(wm + t * 16 + fr) * 32 + rdK];
                bfr[t] = *(const bf16x8*)&Bsl[(wn + t * 16 + fr) * 32 + rdK];
            }
            #pragma unroll
            for (int i = 0; i < 4; ++i)
                #pragma unroll
                for (int j = 0; j < 4; ++j)
                    acc[i][j] = __builtin_amdgcn_mfma_f32_16x16x32_bf16(af[i], bfr[j], acc[i][j], 0, 0, 0);
        }
    }

    float* Cp = Pout + (long)s * (8192L * 128);
    const int cn  = lane & 15;
    const int cr4 = (lane >> 4) * 4;
    #pragma unroll
    for (int i = 0; i < 4; ++i)
        #pragma unroll
        for (int j = 0; j < 4; ++j)
            #pragma unroll
            for (int r = 0; r < 4; ++r) {
                const int row = bm + wm + i * 16 + cr4 + r;
                const int col = wn + j * 16 + cn;
                Cp[(long)row * 128 + col] = acc[i][j][r];
            }
}

// ---------------------------------------------------------------------------
// Reduce 4 split-K partials into (a) xbc (8192 x 32, B/C cols 48..79) and
// (b) xdtS (8192 x 128 padded split: hi of k 0..47 at cols 0..47, lo at
// 64..111, zero pads) — the dt-GEMM A operand.
// ---------------------------------------------------------------------------
__global__ __launch_bounds__(256)
void xdbl_reduce3(const float* __restrict__ Pout, float* __restrict__ xbc,
                  __bf16* __restrict__ xdtS)
{
    const long i = (long)blockIdx.x * 256 + threadIdx.x;   // over 8192*128
    if (i >= 8192L * 128) return;
    const long r  = i >> 7;
    const int  c  = (int)(i & 127);
    const long st = 8192L * 128;
    const long rb = r * 128;

    const int k = c & 63;
    float u = 0.f;
    if (k < 48) {
        const long o = rb + k;
        u = (Pout[o] + Pout[o + st]) + (Pout[o + 2 * st] + Pout[o + 3 * st]);
    }
    const __bf16 hi = (__bf16)u;
    xdtS[rb + c] = (c < 64) ? hi : (__bf16)(u - (float)hi);

    if (c >= 96) {                      // cols 96..127 also emit xbc 0..31
        const int j = c - 96;
        const long o = rb + 48 + j;
        xbc[r * 32 + j] =
            (Pout[o] + Pout[o + st]) + (Pout[o + 2 * st] + Pout[o + 3 * st]);
    }
}

// ---------------------------------------------------------------------------
// Merged input/weight split: x, W_in, W_out, W_x, W_dt (padded 1536x128).
// ---------------------------------------------------------------------------
#define NW0 ((long)BL * 768)
#define NW1 (3072L * 768)
#define NW2 (768L * 1536)
#define NW3 (80L * 1536)
#define NW4 (1536L * 128)
__global__ __launch_bounds__(256)
void split_all(const float* __restrict__ x,
               const float* __restrict__ W_in, const float* __restrict__ W_out,
               const float* __restrict__ W_x, const float* __restrict__ W_dt,
               __bf16* __restrict__ xS,
               __bf16* __restrict__ wInS, __bf16* __restrict__ wOutS,
               __bf16* __restrict__ wXS, __bf16* __restrict__ wDtS)
{
    long i = (long)blockIdx.x * 256 + threadIdx.x;
    if (i < NW0) {
        const long row = i / 768; const int col = (int)(i - row * 768);
        const float a = x[i];
        const __bf16 h = (__bf16)a;
        __bf16* d = xS + row * 1536 + col;
        d[0] = h; d[768] = (__bf16)(a - (float)h);
        return;
    }
    i -= NW0;
    if (i < NW1) {
        const long row = i / 768; const int col = (int)(i - row * 768);
        const float a = W_in[i];
        const __bf16 h = (__bf16)a;
        __bf16* d = wInS + row * 1536 + col;
        d[0] = h; d[768] = (__bf16)(a - (float)h);
        return;
    }
    i -= NW1;
    if (i < NW2) {
        const long row = i / 1536; const int col = (int)(i - row * 1536);
        const float a = W_out[i];
        const __bf16 h = (__bf16)a;
        __bf16* d = wOutS + row * 3072 + col;
        d[0] = h; d[1536] = (__bf16)(a - (float)h);
        return;
    }
    i -= NW2;
    if (i < NW3) {
        const long row = i / 1536; const int col = (int)(i - row * 1536);
        const float a = W_x[i];
        const __bf16 h = (__bf16)a;
        __bf16* d = wXS + row * 3072 + col;
        d[0] = h; d[1536] = (__bf16)(a - (float)h);
        return;
    }
    i -= NW3;
    if (i < NW4) {
        const long row = i >> 7; const int c = (int)(i & 127);
        const int k = c & 63;
        const float a = (k < 48) ? W_dt[row * 48 + k] : 0.f;
        const __bf16 h = (__bf16)a;
        wDtS[row * 128 + c] = (c < 64) ? h : (__bf16)(a - (float)h);
    }
}

// ---------------------------------------------------------------------------
// Depthwise causal conv (width 4) + bias + SiLU -> xcS split-bf16.
// ---------------------------------------------------------------------------
__global__ __launch_bounds__(256)
void conv_silu_kernel(const float* __restrict__ xz,
                      const float* __restrict__ conv_w,
                      const float* __restrict__ conv_b,
                      __bf16* __restrict__ xcS)
{
    const long idx = (long)blockIdx.x * 256 + threadIdx.x;
    const int d  = (int)(idx % D_INNER);
    const long bl = idx / D_INNER;
    const int l  = (int)(bl % SEQ_LEN);

    const float w0 = conv_w[d * 4 + 0];
    const float w1 = conv_w[d * 4 + 1];
    const float w2 = conv_w[d * 4 + 2];
    const float w3 = conv_w[d * 4 + 3];

    const float* base = xz + bl * 3072 + d;
    float s = conv_b[d];
    if (l >= 3) s = fmaf(base[-3 * 3072], w0, s);
    if (l >= 2) s = fmaf(base[-2 * 3072], w1, s);
    if (l >= 1) s = fmaf(base[-1 * 3072], w2, s);
    s = fmaf(base[0], w3, s);
    const float sig = 1.f / (1.f + __expf(-s));
    const float v = s * sig;
    const __bf16 hi = (__bf16)v;
    const __bf16 lo = (__bf16)(v - (float)hi);
    xcS[bl * 3072 + d]        = hi;
    xcS[bl * 3072 + 1536 + d] = lo;
}

// ---------------------------------------------------------------------------
// Scan phase A: per (b, d, chunk): P = prod(a_l), S = local scan (h0=0).
// B/C from xbc (8192 x 32: B_t = [0:16], C_t = [16:32]).
// ---------------------------------------------------------------------------
__global__ __launch_bounds__(256)
void scan_phaseA(const __bf16* __restrict__ xcS, const float* __restrict__ xz,
                 const float* __restrict__ xbc, const float* __restrict__ A_log,
                 float* __restrict__ P, float* __restrict__ S)
{
    const int d = blockIdx.x * 256 + threadIdx.x;
    const int c = blockIdx.y;
    const int b = blockIdx.z;

    float An[16], Pr[16], Sr[16];
    #pragma unroll
    for (int n = 0; n < 16; ++n) {
        An[n] = -__expf(A_log[d * 16 + n]);
        Pr[n] = 1.f;
        Sr[n] = 0.f;
    }

    const long bl0 = (long)b * SEQ_LEN + (long)c * CHUNK;
    for (int l = 0; l < CHUNK; ++l) {
        const long bl = bl0 + l;
        const float dt  = xz[bl * 3072 + d];
        const float x   = (float)xcS[bl * 3072 + d] + (float)xcS[bl * 3072 + 1536 + d];
        const float dtx = dt * x;
        const float* bc = xbc + bl * 32;
        #pragma unroll
        for (int n = 0; n < 16; ++n) {
            const float a = __expf(dt * An[n]);
            Pr[n] *= a;
            Sr[n] = fmaf(a, Sr[n], dtx * bc[n]);
        }
    }

    const long base = ((long)(b * NCHUNK + c) * 16) * D_INNER + d;
    #pragma unroll
    for (int n = 0; n < 16; ++n) {
        P[base + (long)n * D_INNER] = Pr[n];
        S[base + (long)n * D_INNER] = Sr[n];
    }
}

// ---------------------------------------------------------------------------
// Scan phase B (R9): one thread per (b, n, d) — 16x more parallelism than the
// old per-(b,d) version (24 blocks -> 384 blocks; the 38MB P/S/H traffic was
// running on ~10% of the machine). Coalesced over d.
// ---------------------------------------------------------------------------
__global__ __launch_bounds__(256)
void scan_phaseB(const float* __restrict__ P, const float* __restrict__ S,
                 float* __restrict__ H)
{
    const int t = blockIdx.x * 256 + threadIdx.x;   // over BATCH*16*D_INNER
    const int d = t % D_INNER;
    const int r = t / D_INNER;
    const int n = r & 15;
    const int b = r >> 4;

    float h = 0.f;
    for (int c = 0; c < NCHUNK; ++c) {
        const long i = ((long)(b * NCHUNK + c) * 16 + n) * D_INNER + d;
        H[i] = h;
        h = fmaf(P[i], h, S[i]);
    }
}

// ---------------------------------------------------------------------------
// Scan phase C: re-run chunks from h_in, emit y, gate with silu(z), write
// split-bf16 in-place over xcS -> yS.
// ---------------------------------------------------------------------------
__global__ __launch_bounds__(256)
void scan_phaseC(__bf16* xcS_yS, const float* __restrict__ xz,
                 const float* __restrict__ xbc, const float* __restrict__ A_log,
                 const float* __restrict__ Dp, const float* __restrict__ H)
{
    const int d = blockIdx.x * 256 + threadIdx.x;
    const int c = blockIdx.y;
    const int b = blockIdx.z;

    float An[16], h[16];
    const long hbase = ((long)(b * NCHUNK + c) * 16) * D_INNER + d;
    #pragma unroll
    for (int n = 0; n < 16; ++n) {
        An[n] = -__expf(A_log[d * 16 + n]);
        h[n]  = H[hbase + (long)n * D_INNER];
    }
    const float Dd = Dp[d];

    const long bl0 = (long)b * SEQ_LEN + (long)c * CHUNK;
    for (int l = 0; l < CHUNK; ++l) {
        const long bl = bl0 + l;
        const float dt  = xz[bl * 3072 + d];
        const float x   = (float)xcS_yS[bl * 3072 + d] + (float)xcS_yS[bl * 3072 + 1536 + d];
        const float dtx = dt * x;
        const float* bc = xbc + bl * 32;
        float y = Dd * x;
        #pragma unroll
        for (int n = 0; n < 16; ++n) {
            const float a = __expf(dt * An[n]);
            h[n] = fmaf(a, h[n], dtx * bc[n]);
            y = fmaf(h[n], bc[16 + n], y);
        }
        const float z  = xz[bl * 3072 + D_INNER + d];
        const float sz = z / (1.f + __expf(-z));
        const float v  = y * sz;
        const __bf16 hi = (__bf16)v;
        const __bf16 lo = (__bf16)(v - (float)hi);
        xcS_yS[bl * 3072 + d]        = hi;
        xcS_yS[bl * 3072 + 1536 + d] = lo;
    }
}

// ---------------------------------------------------------------------------
extern "C" void kernel_launch(void* const* d_in, const int* in_sizes, int n_in,
                              void* d_out, int out_size, void* d_ws, size_t ws_size,
                              hipStream_t stream)
{
    const float* x      = (const float*)d_in[0];   // (4,2048,768)
    const float* W_in   = (const float*)d_in[1];   // (3072,768)
    const float* conv_w = (const float*)d_in[2];   // (1536,1,4)
    const float* conv_b = (const float*)d_in[3];   // (1536,)
    const float* W_x    = (const float*)d_in[4];   // (80,1536)
    const float* W_dt   = (const float*)d_in[5];   // (1536,48)
    const float* b_dt   = (const float*)d_in[6];   // (1536,)
    const float* A_log  = (const float*)d_in[7];   // (1536,16)
    const float* D_p    = (const float*)d_in[8];   // (1536,)
    const float* W_out  = (const float*)d_in[9];   // (768,1536)
    float* out = (float*)d_out;                    // (4,2048,768)

    // ---- workspace carve, ~202 MB ---------------------------------------
    char* p = (char*)d_ws;
    auto take = [&](size_t bytes) { char* r = p; p += (bytes + 255) & ~(size_t)255; return r; };

    float*  xz    = (float*)take((size_t)BL * 3072 * 4);    // 100.7 MB (dt | z)
    float*  H     = (float*)take((size_t)BATCH * NCHUNK * 16 * D_INNER * 4); // 12.6 MB
    __bf16* wOutS = (__bf16*)take(768L * 3072 * 2);         //   4.7 MB
    __bf16* wXS   = (__bf16*)take(128L * 3072 * 2);         //   0.8 MB (80 valid)
    __bf16* wDtS  = (__bf16*)take(1536L * 128 * 2);         //   0.4 MB
    __bf16* xdtS  = (__bf16*)take(8192L * 128 * 2);         //   2.1 MB
    float*  xbc   = (float*)take(8192L * 32 * 4);           //   1.0 MB
    float*  Pout  = (float*)take(4L * 8192 * 128 * 4);      //  16.8 MB (-> P overlay)
    float*  S     = (float*)take((size_t)BATCH * NCHUNK * 16 * D_INNER * 4); // 12.6 MB
    float*  P     = Pout;   // Pout dead after xdbl_reduce3; P needs 12.6 MB

    // REGION (50.4 MB), time-multiplexed:
    //   phase 1:   xS (25.2MB) + wInS (9.4MB)
    //   phase 2-8: xcS (8192x3072 bf16), phaseC overwrites in-place -> yS
    char* region = take(50331648);
    __bf16* xS   = (__bf16*)region;
    __bf16* wInS = (__bf16*)(region + 25165824);
    __bf16* xcS  = (__bf16*)region;
    __bf16* yS   = (__bf16*)region;

    // 0) split conversions (x + weights, one launch)
    {
        const long n = NW0 + NW1 + NW2 + NW3 + NW4;
        split_all<<<(int)((n + 255) / 256), 256, 0, stream>>>(
            x, W_in, W_out, W_x, W_dt, xS, wInS, wOutS, wXS, wDtS);
    }
    // 1) xz = x @ W_in^T  (BK=64 MFMA, M=8192, N=3072, K=768)
    {
        dim3 grid(3072 / 128, BL / 128);
        gemm_in<0><<<grid, 256, 0, stream>>>(xS, wInS, xz, nullptr,
                                             BL, 3072, 768, 3072);
    }
    // 2) conv + bias + SiLU -> xcS (overlays xS)
    {
        const long total = (long)BL * D_INNER;
        conv_silu_kernel<<<(int)(total / 256), 256, 0, stream>>>(xz, conv_w, conv_b, xcS);
    }
    // 3) x_dbl split-K MFMA -> Pout
    {
        dim3 grid(4, BL / 128);
        gemm_xdbl<<<grid, 256, 0, stream>>>(xcS, wXS, Pout);
    }
    // 4) reduce partials -> xbc + xdtS
    {
        const long n = 8192L * 128;
        xdbl_reduce3<<<(int)((n + 255) / 256), 256, 0, stream>>>(Pout, xbc, xdtS);
    }
    // 5) dt = softplus(xdt @ W_dt^T + b_dt)  (BK=64 MFMA, K=64 padded)
    {
        dim3 grid(1536 / 128, BL / 128);
        gemm_in<1><<<grid, 256, 0, stream>>>(xdtS, wDtS, xz, b_dt,
                                             BL, 1536, 64, 3072);
    }
    // 6) scan phase A  (P overlays dead Pout)
    {
        dim3 grid(D_INNER / 256, NCHUNK, BATCH);
        scan_phaseA<<<grid, 256, 0, stream>>>(xcS, xz, xbc, A_log, P, S);
    }
    // 7) scan phase B (per-(b,n,d): 384 blocks)
    scan_phaseB<<<(BATCH * 16 * D_INNER) / 256, 256, 0, stream>>>(P, S, H);
    // 8) scan phase C: xcS -> yS in-place
    {
        dim3 grid(D_INNER / 256, NCHUNK, BATCH);
        scan_phaseC<<<grid, 256, 0, stream>>>(xcS, xz, xbc, A_log, D_p, H);
    }
    // 9) out = y @ W_out^T  (BK=64 MFMA, M=8192, N=768, K=1536)
    {
        dim3 grid(768 / 128, BL / 128);
        gemm_in<0><<<grid, 256, 0, stream>>>(yS, wOutS, out, nullptr,
                                             BL, 768, 1536, 768);
    }
}

// Round 10
// 529.761 us; speedup vs baseline: 1.3251x; 1.0796x over previous
//
#include <hip/hip_runtime.h>
#include <hip/hip_bf16.h>
#include <math.h>

// Problem constants (fixed by reference)
#define D_MODEL   768
#define D_STATE   16
#define D_CONV    4
#define D_INNER   1536
#define DT_RANK   48
#define BATCH     4
#define SEQ_LEN   2048
#define BL        (BATCH * SEQ_LEN)        // 8192 rows
#define NCHUNK    32
#define CHUNK     (SEQ_LEN / NCHUNK)       // 64

typedef __bf16 bf16x8 __attribute__((ext_vector_type(8)));
typedef float  f32x4  __attribute__((ext_vector_type(4)));

__device__ __forceinline__ void async_copy16(const void* g, void* l) {
    __builtin_amdgcn_global_load_lds(
        (const __attribute__((address_space(1))) void*)g,
        (__attribute__((address_space(3))) void*)l,
        16, 0, 0);
}

// ---------------------------------------------------------------------------
// Split-bf16 MFMA GEMM (NT), SINGLE-PASS K (R10): per 32-k tile, stage all
// four panels once — LDS row r (128B) = [Ah(32k) | Al(32k)], ditto B — and
// fire all three products Ah*Bh + Ah*Bl + Al*Bh from that single stage.
// vs R9's three K sub-loops: 24 barrier-pairs instead of 36 (the vmcnt(0)
// drain before s_barrier is the structural stall) and hi panels fetched from
// HBM once instead of twice (staged bytes -33%).  48 MFMA per 16 ds_read_b128.
// A: M x 2K bf16 [A_hi | A_lo], B: N x 2K [B_hi | B_lo]. 128x128 tile,
// 4 waves of 64x64 (4x4 of 16x16x32). K % 32 == 0.
// LDS swizzle = R8 (verified conflicts=0): slot s of row r holds chunk
// s ^ (r&7); chunk q<4 = hi k q*8.., q>=4 = lo k (q-4)*8.. (global-side map).
// EPI 0: plain store.  EPI 1: softplus(v + bias[col]) (dt epilogue).
// ---------------------------------------------------------------------------
template <int EPI>
__global__ __launch_bounds__(256)
void gemm_f(const __bf16* __restrict__ A, const __bf16* __restrict__ B,
            float* __restrict__ C, const float* __restrict__ bias,
            int M, int N, int K, int ldc)
{
    __shared__ __bf16 Asl[128 * 64];
    __shared__ __bf16 Bsl[128 * 64];

    const int tid  = threadIdx.x;
    const int lane = tid & 63;
    const int w    = tid >> 6;
    const int wm   = (w >> 1) * 64;
    const int wn   = (w & 1) * 64;

    const int bm = blockIdx.y * 128;
    const int bn = blockIdx.x * 128;

    const long lda = 2L * K;
    const long ldb = 2L * K;

    f32x4 acc[4][4];
    #pragma unroll
    for (int i = 0; i < 4; ++i)
        #pragma unroll
        for (int j = 0; j < 4; ++j)
            acc[i][j] = (f32x4){0.f, 0.f, 0.f, 0.f};

    // staging: lane l -> row w*32 + (l>>3); slot l&7 gets chunk q=(l&7)^((l>>3)&7)
    // chunk q: q<4 -> hi segment (+q*8), q>=4 -> lo segment (+K+(q-4)*8)
    const int srow = w * 32 + (lane >> 3);
    const int q    = (lane & 7) ^ ((lane >> 3) & 7);
    const int qoff = (q < 4) ? q * 8 : K + (q - 4) * 8;
    const __bf16* Abase = A + (long)(bm + srow) * lda + qoff;
    const __bf16* Bbase = B + (long)(bn + srow) * ldb + qoff;
    char* AslW = (char*)Asl + (w * 32) * 128;
    char* BslW = (char*)Bsl + (w * 32) * 128;

    const int fr = lane & 15;
    const int g4 = lane >> 4;          // k-chunk group 0..3 within 32-k tile
    const long lda8 = 8 * lda, ldb8 = 8 * ldb;

    for (int kk = 0; kk < K; kk += 32) {
        __syncthreads();
        #pragma unroll
        for (int j = 0; j < 4; ++j) {
            async_copy16(Abase + j * lda8 + kk, AslW + j * 1024);
            async_copy16(Bbase + j * ldb8 + kk, BslW + j * 1024);
        }
        __syncthreads();

        bf16x8 ah[4], al[4], bh[4], bl[4];
        #pragma unroll
        for (int t = 0; t < 4; ++t) {
            const int ra = wm + t * 16 + fr;
            const int rb = wn + t * 16 + fr;
            ah[t] = *(const bf16x8*)&Asl[ra * 64 + ((g4       ^ (ra & 7)) * 8)];
            al[t] = *(const bf16x8*)&Asl[ra * 64 + (((4 + g4) ^ (ra & 7)) * 8)];
            bh[t] = *(const bf16x8*)&Bsl[rb * 64 + ((g4       ^ (rb & 7)) * 8)];
            bl[t] = *(const bf16x8*)&Bsl[rb * 64 + (((4 + g4) ^ (rb & 7)) * 8)];
        }
        #pragma unroll
        for (int i = 0; i < 4; ++i)
            #pragma unroll
            for (int j = 0; j < 4; ++j) {
                acc[i][j] = __builtin_amdgcn_mfma_f32_16x16x32_bf16(ah[i], bh[j], acc[i][j], 0, 0, 0);
                acc[i][j] = __builtin_amdgcn_mfma_f32_16x16x32_bf16(ah[i], bl[j], acc[i][j], 0, 0, 0);
                acc[i][j] = __builtin_amdgcn_mfma_f32_16x16x32_bf16(al[i], bh[j], acc[i][j], 0, 0, 0);
            }
    }

    // C/D layout (m89-verified): col = lane&15, row = (lane>>4)*4 + reg
    const int cn  = lane & 15;
    const int cr4 = (lane >> 4) * 4;
    #pragma unroll
    for (int i = 0; i < 4; ++i)
        #pragma unroll
        for (int j = 0; j < 4; ++j)
            #pragma unroll
            for (int r = 0; r < 4; ++r) {
                const int row = bm + wm + i * 16 + cr4 + r;
                const int col = bn + wn + j * 16 + cn;
                float v = acc[i][j][r];
                if (EPI == 1) {
                    v += bias[col];
                    v = fmaxf(v, 0.f) + log1pf(__expf(-fabsf(v)));  // stable softplus
                }
                C[(long)row * ldc + col] = v;
            }
}

// ---------------------------------------------------------------------------
// x_dbl split-K MFMA GEMM, single-pass K (R10): A = xcS (8192 x 3072 split),
// B = W_xS (128-row padded, 80 valid), K=1536 -> 48 k-tiles split 4 ways.
// grid(4, 64); partials to Pout[s][8192][128].
// ---------------------------------------------------------------------------
__global__ __launch_bounds__(256)
void gemm_xdbl(const __bf16* __restrict__ A, const __bf16* __restrict__ B,
               float* __restrict__ Pout)
{
    __shared__ __bf16 Asl[128 * 64];
    __shared__ __bf16 Bsl[128 * 64];

    const int tid  = threadIdx.x;
    const int lane = tid & 63;
    const int w    = tid >> 6;
    const int wm   = (w >> 1) * 64;
    const int wn   = (w & 1) * 64;

    const int s  = blockIdx.x;           // split-K index 0..3
    const int bm = blockIdx.y * 128;
    const int K  = 1536;
    const long lda = 3072, ldb = 3072;

    f32x4 acc[4][4];
    #pragma unroll
    for (int i = 0; i < 4; ++i)
        #pragma unroll
        for (int j = 0; j < 4; ++j)
            acc[i][j] = (f32x4){0.f, 0.f, 0.f, 0.f};

    const int srow = w * 32 + (lane >> 3);
    const int q    = (lane & 7) ^ ((lane >> 3) & 7);
    const int qoff = (q < 4) ? q * 8 : K + (q - 4) * 8;
    const __bf16* Abase = A + (long)(bm + srow) * lda + qoff;
    const __bf16* Bbase = B + (long)srow * ldb + qoff;
    char* AslW = (char*)Asl + (w * 32) * 128;
    char* BslW = (char*)Bsl + (w * 32) * 128;

    const int fr = lane & 15;
    const int g4 = lane >> 4;
    const long lda8 = 8 * lda, ldb8 = 8 * ldb;

    for (int kt = s * 12; kt < (s + 1) * 12; ++kt) {
        const int kk = kt * 32;
        __syncthreads();
        #pragma unroll
        for (int j = 0; j < 4; ++j) {
            async_copy16(Abase + j * lda8 + kk, AslW + j * 1024);
            async_copy16(Bbase + j * ldb8 + kk, BslW + j * 1024);
        }
        __syncthreads();

        bf16x8 ah[4], al[4], bh[4], bl[4];
        #pragma unroll
        for (int t = 0; t < 4; ++t) {
            const int ra = wm + t * 16 + fr;
            const int rb = wn + t * 16 + fr;
            ah[t] = *(const bf16x8*)&Asl[ra * 64 + ((g4       ^ (ra & 7)) * 8)];
            al[t] = *(const bf16x8*)&Asl[ra * 64 + (((4 + g4) ^ (ra & 7)) * 8)];
            bh[t] = *(const bf16x8*)&Bsl[rb * 64 + ((g4       ^ (rb & 7)) * 8)];
            bl[t] = *(const bf16x8*)&Bsl[rb * 64 + (((4 + g4) ^ (rb & 7)) * 8)];
        }
        #pragma unroll
        for (int i = 0; i < 4; ++i)
            #pragma unroll
            for (int j = 0; j < 4; ++j) {
                acc[i][j] = __builtin_amdgcn_mfma_f32_16x16x32_bf16(ah[i], bh[j], acc[i][j], 0, 0, 0);
                acc[i][j] = __builtin_amdgcn_mfma_f32_16x16x32_bf16(ah[i], bl[j], acc[i][j], 0, 0, 0);
                acc[i][j] = __builtin_amdgcn_mfma_f32_16x16x32_bf16(al[i], bh[j], acc[i][j], 0, 0, 0);
            }
    }

    float* Cp = Pout + (long)s * (8192L * 128);
    const int cn  = lane & 15;
    const int cr4 = (lane >> 4) * 4;
    #pragma unroll
    for (int i = 0; i < 4; ++i)
        #pragma unroll
        for (int j = 0; j < 4; ++j)
            #pragma unroll
            for (int r = 0; r < 4; ++r) {
                const int row = bm + wm + i * 16 + cr4 + r;
                const int col = wn + j * 16 + cn;
                Cp[(long)row * 128 + col] = acc[i][j][r];
            }
}

// ---------------------------------------------------------------------------
// Reduce 4 split-K partials into (a) xbc (8192 x 32, B/C cols 48..79) and
// (b) xdtS (8192 x 128 padded split: hi of k 0..47 at cols 0..47, lo at
// 64..111, zero pads) — the dt-GEMM A operand.
// ---------------------------------------------------------------------------
__global__ __launch_bounds__(256)
void xdbl_reduce3(const float* __restrict__ Pout, float* __restrict__ xbc,
                  __bf16* __restrict__ xdtS)
{
    const long i = (long)blockIdx.x * 256 + threadIdx.x;   // over 8192*128
    if (i >= 8192L * 128) return;
    const long r  = i >> 7;
    const int  c  = (int)(i & 127);
    const long st = 8192L * 128;
    const long rb = r * 128;

    const int k = c & 63;
    float u = 0.f;
    if (k < 48) {
        const long o = rb + k;
        u = (Pout[o] + Pout[o + st]) + (Pout[o + 2 * st] + Pout[o + 3 * st]);
    }
    const __bf16 hi = (__bf16)u;
    xdtS[rb + c] = (c < 64) ? hi : (__bf16)(u - (float)hi);

    if (c >= 96) {                      // cols 96..127 also emit xbc 0..31
        const int j = c - 96;
        const long o = rb + 48 + j;
        xbc[r * 32 + j] =
            (Pout[o] + Pout[o + st]) + (Pout[o + 2 * st] + Pout[o + 3 * st]);
    }
}

// ---------------------------------------------------------------------------
// Merged input/weight split: x, W_in, W_out, W_x, W_dt (padded 1536x128).
// ---------------------------------------------------------------------------
#define NW0 ((long)BL * 768)
#define NW1 (3072L * 768)
#define NW2 (768L * 1536)
#define NW3 (80L * 1536)
#define NW4 (1536L * 128)
__global__ __launch_bounds__(256)
void split_all(const float* __restrict__ x,
               const float* __restrict__ W_in, const float* __restrict__ W_out,
               const float* __restrict__ W_x, const float* __restrict__ W_dt,
               __bf16* __restrict__ xS,
               __bf16* __restrict__ wInS, __bf16* __restrict__ wOutS,
               __bf16* __restrict__ wXS, __bf16* __restrict__ wDtS)
{
    long i = (long)blockIdx.x * 256 + threadIdx.x;
    if (i < NW0) {
        const long row = i / 768; const int col = (int)(i - row * 768);
        const float a = x[i];
        const __bf16 h = (__bf16)a;
        __bf16* d = xS + row * 1536 + col;
        d[0] = h; d[768] = (__bf16)(a - (float)h);
        return;
    }
    i -= NW0;
    if (i < NW1) {
        const long row = i / 768; const int col = (int)(i - row * 768);
        const float a = W_in[i];
        const __bf16 h = (__bf16)a;
        __bf16* d = wInS + row * 1536 + col;
        d[0] = h; d[768] = (__bf16)(a - (float)h);
        return;
    }
    i -= NW1;
    if (i < NW2) {
        const long row = i / 1536; const int col = (int)(i - row * 1536);
        const float a = W_out[i];
        const __bf16 h = (__bf16)a;
        __bf16* d = wOutS + row * 3072 + col;
        d[0] = h; d[1536] = (__bf16)(a - (float)h);
        return;
    }
    i -= NW2;
    if (i < NW3) {
        const long row = i / 1536; const int col = (int)(i - row * 1536);
        const float a = W_x[i];
        const __bf16 h = (__bf16)a;
        __bf16* d = wXS + row * 3072 + col;
        d[0] = h; d[1536] = (__bf16)(a - (float)h);
        return;
    }
    i -= NW3;
    if (i < NW4) {
        const long row = i >> 7; const int c = (int)(i & 127);
        const int k = c & 63;
        const float a = (k < 48) ? W_dt[row * 48 + k] : 0.f;
        const __bf16 h = (__bf16)a;
        wDtS[row * 128 + c] = (c < 64) ? h : (__bf16)(a - (float)h);
    }
}

// ---------------------------------------------------------------------------
// Depthwise causal conv (width 4) + bias + SiLU -> xcS split-bf16.
// ---------------------------------------------------------------------------
__global__ __launch_bounds__(256)
void conv_silu_kernel(const float* __restrict__ xz,
                      const float* __restrict__ conv_w,
                      const float* __restrict__ conv_b,
                      __bf16* __restrict__ xcS)
{
    const long idx = (long)blockIdx.x * 256 + threadIdx.x;
    const int d  = (int)(idx % D_INNER);
    const long bl = idx / D_INNER;
    const int l  = (int)(bl % SEQ_LEN);

    const float w0 = conv_w[d * 4 + 0];
    const float w1 = conv_w[d * 4 + 1];
    const float w2 = conv_w[d * 4 + 2];
    const float w3 = conv_w[d * 4 + 3];

    const float* base = xz + bl * 3072 + d;
    float s = conv_b[d];
    if (l >= 3) s = fmaf(base[-3 * 3072], w0, s);
    if (l >= 2) s = fmaf(base[-2 * 3072], w1, s);
    if (l >= 1) s = fmaf(base[-1 * 3072], w2, s);
    s = fmaf(base[0], w3, s);
    const float sig = 1.f / (1.f + __expf(-s));
    const float v = s * sig;
    const __bf16 hi = (__bf16)v;
    const __bf16 lo = (__bf16)(v - (float)hi);
    xcS[bl * 3072 + d]        = hi;
    xcS[bl * 3072 + 1536 + d] = lo;
}

// ---------------------------------------------------------------------------
// Scan phase A: per (b, d, chunk): P = prod(a_l), S = local scan (h0=0).
// B/C from xbc (8192 x 32: B_t = [0:16], C_t = [16:32]).
// ---------------------------------------------------------------------------
__global__ __launch_bounds__(256)
void scan_phaseA(const __bf16* __restrict__ xcS, const float* __restrict__ xz,
                 const float* __restrict__ xbc, const float* __restrict__ A_log,
                 float* __restrict__ P, float* __restrict__ S)
{
    const int d = blockIdx.x * 256 + threadIdx.x;
    const int c = blockIdx.y;
    const int b = blockIdx.z;

    float An[16], Pr[16], Sr[16];
    #pragma unroll
    for (int n = 0; n < 16; ++n) {
        An[n] = -__expf(A_log[d * 16 + n]);
        Pr[n] = 1.f;
        Sr[n] = 0.f;
    }

    const long bl0 = (long)b * SEQ_LEN + (long)c * CHUNK;
    for (int l = 0; l < CHUNK; ++l) {
        const long bl = bl0 + l;
        const float dt  = xz[bl * 3072 + d];
        const float x   = (float)xcS[bl * 3072 + d] + (float)xcS[bl * 3072 + 1536 + d];
        const float dtx = dt * x;
        const float* bc = xbc + bl * 32;
        #pragma unroll
        for (int n = 0; n < 16; ++n) {
            const float a = __expf(dt * An[n]);
            Pr[n] *= a;
            Sr[n] = fmaf(a, Sr[n], dtx * bc[n]);
        }
    }

    const long base = ((long)(b * NCHUNK + c) * 16) * D_INNER + d;
    #pragma unroll
    for (int n = 0; n < 16; ++n) {
        P[base + (long)n * D_INNER] = Pr[n];
        S[base + (long)n * D_INNER] = Sr[n];
    }
}

// ---------------------------------------------------------------------------
// Scan phase B: one thread per (b, n, d) — 384 blocks, coalesced over d.
// ---------------------------------------------------------------------------
__global__ __launch_bounds__(256)
void scan_phaseB(const float* __restrict__ P, const float* __restrict__ S,
                 float* __restrict__ H)
{
    const int t = blockIdx.x * 256 + threadIdx.x;   // over BATCH*16*D_INNER
    const int d = t % D_INNER;
    const int r = t / D_INNER;
    const int n = r & 15;
    const int b = r >> 4;

    float h = 0.f;
    for (int c = 0; c < NCHUNK; ++c) {
        const long i = ((long)(b * NCHUNK + c) * 16 + n) * D_INNER + d;
        H[i] = h;
        h = fmaf(P[i], h, S[i]);
    }
}

// ---------------------------------------------------------------------------
// Scan phase C: re-run chunks from h_in, emit y, gate with silu(z), write
// split-bf16 in-place over xcS -> yS.
// ---------------------------------------------------------------------------
__global__ __launch_bounds__(256)
void scan_phaseC(__bf16* xcS_yS, const float* __restrict__ xz,
                 const float* __restrict__ xbc, const float* __restrict__ A_log,
                 const float* __restrict__ Dp, const float* __restrict__ H)
{
    const int d = blockIdx.x * 256 + threadIdx.x;
    const int c = blockIdx.y;
    const int b = blockIdx.z;

    float An[16], h[16];
    const long hbase = ((long)(b * NCHUNK + c) * 16) * D_INNER + d;
    #pragma unroll
    for (int n = 0; n < 16; ++n) {
        An[n] = -__expf(A_log[d * 16 + n]);
        h[n]  = H[hbase + (long)n * D_INNER];
    }
    const float Dd = Dp[d];

    const long bl0 = (long)b * SEQ_LEN + (long)c * CHUNK;
    for (int l = 0; l < CHUNK; ++l) {
        const long bl = bl0 + l;
        const float dt  = xz[bl * 3072 + d];
        const float x   = (float)xcS_yS[bl * 3072 + d] + (float)xcS_yS[bl * 3072 + 1536 + d];
        const float dtx = dt * x;
        const float* bc = xbc + bl * 32;
        float y = Dd * x;
        #pragma unroll
        for (int n = 0; n < 16; ++n) {
            const float a = __expf(dt * An[n]);
            h[n] = fmaf(a, h[n], dtx * bc[n]);
            y = fmaf(h[n], bc[16 + n], y);
        }
        const float z  = xz[bl * 3072 + D_INNER + d];
        const float sz = z / (1.f + __expf(-z));
        const float v  = y * sz;
        const __bf16 hi = (__bf16)v;
        const __bf16 lo = (__bf16)(v - (float)hi);
        xcS_yS[bl * 3072 + d]        = hi;
        xcS_yS[bl * 3072 + 1536 + d] = lo;
    }
}

// ---------------------------------------------------------------------------
extern "C" void kernel_launch(void* const* d_in, const int* in_sizes, int n_in,
                              void* d_out, int out_size, void* d_ws, size_t ws_size,
                              hipStream_t stream)
{
    const float* x      = (const float*)d_in[0];   // (4,2048,768)
    const float* W_in   = (const float*)d_in[1];   // (3072,768)
    const float* conv_w = (const float*)d_in[2];   // (1536,1,4)
    const float* conv_b = (const float*)d_in[3];   // (1536,)
    const float* W_x    = (const float*)d_in[4];   // (80,1536)
    const float* W_dt   = (const float*)d_in[5];   // (1536,48)
    const float* b_dt   = (const float*)d_in[6];   // (1536,)
    const float* A_log  = (const float*)d_in[7];   // (1536,16)
    const float* D_p    = (const float*)d_in[8];   // (1536,)
    const float* W_out  = (const float*)d_in[9];   // (768,1536)
    float* out = (float*)d_out;                    // (4,2048,768)

    // ---- workspace carve, ~202 MB ---------------------------------------
    char* p = (char*)d_ws;
    auto take = [&](size_t bytes) { char* r = p; p += (bytes + 255) & ~(size_t)255; return r; };

    float*  xz    = (float*)take((size_t)BL * 3072 * 4);    // 100.7 MB (dt | z)
    float*  H     = (float*)take((size_t)BATCH * NCHUNK * 16 * D_INNER * 4); // 12.6 MB
    __bf16* wOutS = (__bf16*)take(768L * 3072 * 2);         //   4.7 MB
    __bf16* wXS   = (__bf16*)take(128L * 3072 * 2);         //   0.8 MB (80 valid)
    __bf16* wDtS  = (__bf16*)take(1536L * 128 * 2);         //   0.4 MB
    __bf16* xdtS  = (__bf16*)take(8192L * 128 * 2);         //   2.1 MB
    float*  xbc   = (float*)take(8192L * 32 * 4);           //   1.0 MB
    float*  Pout  = (float*)take(4L * 8192 * 128 * 4);      //  16.8 MB (-> P overlay)
    float*  S     = (float*)take((size_t)BATCH * NCHUNK * 16 * D_INNER * 4); // 12.6 MB
    float*  P     = Pout;   // Pout dead after xdbl_reduce3; P needs 12.6 MB

    // REGION (50.4 MB), time-multiplexed:
    //   phase 1:   xS (25.2MB) + wInS (9.4MB)
    //   phase 2-8: xcS (8192x3072 bf16), phaseC overwrites in-place -> yS
    char* region = take(50331648);
    __bf16* xS   = (__bf16*)region;
    __bf16* wInS = (__bf16*)(region + 25165824);
    __bf16* xcS  = (__bf16*)region;
    __bf16* yS   = (__bf16*)region;

    // 0) split conversions (x + weights, one launch)
    {
        const long n = NW0 + NW1 + NW2 + NW3 + NW4;
        split_all<<<(int)((n + 255) / 256), 256, 0, stream>>>(
            x, W_in, W_out, W_x, W_dt, xS, wInS, wOutS, wXS, wDtS);
    }
    // 1) xz = x @ W_in^T  (single-pass MFMA, M=8192, N=3072, K=768)
    {
        dim3 grid(3072 / 128, BL / 128);
        gemm_f<0><<<grid, 256, 0, stream>>>(xS, wInS, xz, nullptr,
                                            BL, 3072, 768, 3072);
    }
    // 2) conv + bias + SiLU -> xcS (overlays xS)
    {
        const long total = (long)BL * D_INNER;
        conv_silu_kernel<<<(int)(total / 256), 256, 0, stream>>>(xz, conv_w, conv_b, xcS);
    }
    // 3) x_dbl split-K MFMA -> Pout
    {
        dim3 grid(4, BL / 128);
        gemm_xdbl<<<grid, 256, 0, stream>>>(xcS, wXS, Pout);
    }
    // 4) reduce partials -> xbc + xdtS
    {
        const long n = 8192L * 128;
        xdbl_reduce3<<<(int)((n + 255) / 256), 256, 0, stream>>>(Pout, xbc, xdtS);
    }
    // 5) dt = softplus(xdt @ W_dt^T + b_dt)  (single-pass MFMA, K=64 padded)
    {
        dim3 grid(1536 / 128, BL / 128);
        gemm_f<1><<<grid, 256, 0, stream>>>(xdtS, wDtS, xz, b_dt,
                                            BL, 1536, 64, 3072);
    }
    // 6) scan phase A  (P overlays dead Pout)
    {
        dim3 grid(D_INNER / 256, NCHUNK, BATCH);
        scan_phaseA<<<grid, 256, 0, stream>>>(xcS, xz, xbc, A_log, P, S);
    }
    // 7) scan phase B (per-(b,n,d): 384 blocks)
    scan_phaseB<<<(BATCH * 16 * D_INNER) / 256, 256, 0, stream>>>(P, S, H);
    // 8) scan phase C: xcS -> yS in-place
    {
        dim3 grid(D_INNER / 256, NCHUNK, BATCH);
        scan_phaseC<<<grid, 256, 0, stream>>>(xcS, xz, xbc, A_log, D_p, H);
    }
    // 9) out = y @ W_out^T  (single-pass MFMA, M=8192, N=768, K=1536)
    {
        dim3 grid(768 / 128, BL / 128);
        gemm_f<0><<<grid, 256, 0, stream>>>(yS, wOutS, out, nullptr,
                                            BL, 768, 1536, 768);
    }
}